// Round 1
// baseline (385.877 us; speedup 1.0000x reference)
//
#include <hip/hip_runtime.h>

#define B_    32
#define N_    512
#define D_    128
#define ROWS  (B_ * N_)          // 16384
#define BIGF  9.0e15f
#define SCALE_ 0.17677669529663687f   // 1/sqrt(32)

typedef __bf16 bf16x8 __attribute__((ext_vector_type(8)));
typedef float  f32x4  __attribute__((ext_vector_type(4)));

static __device__ __forceinline__ f32x4 mfma16(bf16x8 a, bf16x8 b, f32x4 c) {
  return __builtin_amdgcn_mfma_f32_16x16x32_bf16(a, b, c, 0, 0, 0);
}

// ---------------------------------------------------------------------------
// Kernel 1: q/k/v = relu(x @ w + b), bf16 outputs.
// mat = 0..5 -> (g0:q,k,v),(g1:q,k,v). q,k stored [b][n][128]; v stored
// transposed per batch: vt[b][dim][key]  (so attention PV B-frags are
// contiguous 16B loads).
// ---------------------------------------------------------------------------
__global__ __launch_bounds__(256) void qkv_kernel(
    const float* __restrict__ x0, const float* __restrict__ x1,
    const float* __restrict__ wq0, const float* __restrict__ bq0,
    const float* __restrict__ wk0, const float* __restrict__ bk0,
    const float* __restrict__ wv0, const float* __restrict__ bv0,
    const float* __restrict__ wq1, const float* __restrict__ bq1,
    const float* __restrict__ wk1, const float* __restrict__ bk1,
    const float* __restrict__ wv1, const float* __restrict__ bv1,
    __bf16* __restrict__ wsb)
{
  __shared__ __bf16 wT[128][136];    // wT[n][k] = w[k][n], +8 pad (bank-safe)
  __shared__ __bf16 vtile[128][72];  // [dim][key_local], +8 pad

  const int bx  = blockIdx.x;
  const int mat = bx >> 8;           // 0..5
  const int R0  = (bx & 255) * 64;   // row tile base
  const int t    = threadIdx.x;
  const int lane = t & 63, wave = t >> 6;
  const int quad = lane >> 4, ln = lane & 15;

  const float* xs = (mat < 3) ? x0 : x1;
  const float* wsel; const float* bsel;
  switch (mat) {
    case 0: wsel = wq0; bsel = bq0; break;
    case 1: wsel = wk0; bsel = bk0; break;
    case 2: wsel = wv0; bsel = bv0; break;
    case 3: wsel = wq1; bsel = bq1; break;
    case 4: wsel = wk1; bsel = bk1; break;
    default: wsel = wv1; bsel = bv1; break;
  }
  const int type = mat % 3;          // 0=q,1=k,2=v
  __bf16* outp = wsb + (size_t)mat * (ROWS * D_);

  // stage wT[n][k] = bf16(w[k][n]) -- coalesced global reads, scattered LDS writes
  {
    const int k = t >> 1, nh = (t & 1) * 64;
    const float4* wrow = (const float4*)(wsel + (size_t)k * 128 + nh);
    #pragma unroll
    for (int v = 0; v < 16; ++v) {
      float4 f = wrow[v];
      wT[nh + v * 4 + 0][k] = (__bf16)f.x;
      wT[nh + v * 4 + 1][k] = (__bf16)f.y;
      wT[nh + v * 4 + 2][k] = (__bf16)f.z;
      wT[nh + v * 4 + 3][k] = (__bf16)f.w;
    }
  }
  __syncthreads();

  // A frags from x (fp32 -> bf16): wave handles rows R0 + wave*16 .. +15
  bf16x8 af[4];
  {
    const int row = R0 + wave * 16 + ln;
    #pragma unroll
    for (int ks = 0; ks < 4; ++ks) {
      const float4* xp = (const float4*)(xs + (size_t)row * 128 + ks * 32 + quad * 8);
      float4 a = xp[0], b = xp[1];
      bf16x8 v;
      v[0] = (__bf16)a.x; v[1] = (__bf16)a.y; v[2] = (__bf16)a.z; v[3] = (__bf16)a.w;
      v[4] = (__bf16)b.x; v[5] = (__bf16)b.y; v[6] = (__bf16)b.z; v[7] = (__bf16)b.w;
      af[ks] = v;
    }
  }

  f32x4 acc[8];
  #pragma unroll
  for (int nt = 0; nt < 8; ++nt) { f32x4 z = {0.f, 0.f, 0.f, 0.f}; acc[nt] = z; }
  #pragma unroll
  for (int ks = 0; ks < 4; ++ks) {
    #pragma unroll
    for (int nt = 0; nt < 8; ++nt) {
      bf16x8 bfrag = *(const bf16x8*)&wT[nt * 16 + ln][ks * 32 + quad * 8];
      acc[nt] = mfma16(af[ks], bfrag, acc[nt]);
    }
  }

  if (type != 2) {
    // q/k: direct store [row][col]
    #pragma unroll
    for (int nt = 0; nt < 8; ++nt) {
      const int col = nt * 16 + ln;
      const float bv = bsel[col];
      #pragma unroll
      for (int r = 0; r < 4; ++r) {
        float v = fmaxf(acc[nt][r] + bv, 0.f);
        outp[(size_t)(R0 + wave * 16 + quad * 4 + r) * D_ + col] = (__bf16)v;
      }
    }
  } else {
    // v: transpose via LDS, then coalesced 16B stores to vt[b][dim][key]
    #pragma unroll
    for (int nt = 0; nt < 8; ++nt) {
      const int col = nt * 16 + ln;
      const float bv = bsel[col];
      #pragma unroll
      for (int r = 0; r < 4; ++r) {
        float v = fmaxf(acc[nt][r] + bv, 0.f);
        vtile[col][wave * 16 + quad * 4 + r] = (__bf16)v;
      }
    }
    __syncthreads();
    const int b = R0 >> 9, kb2 = R0 & 511;
    const int dim = t >> 1, off = (t & 1) * 32;
    uint4* dst = (uint4*)(outp + (size_t)b * (D_ * N_) + (size_t)dim * N_ + kb2 + off);
    const uint4* srcp = (const uint4*)&vtile[dim][off];
    #pragma unroll
    for (int i = 0; i < 4; ++i) dst[i] = srcp[i];
  }
}

// ---------------------------------------------------------------------------
// Kernel 2: fused masked attention + wo projection + relu.
// block = (attend a, batch b, q-tile of 64 rows); wave = head.
// a=0: inner0(q0,k0,v0,m00)  a=1: inner1(q1,k1,v1,m11)
// a=2: inter0(q0,k1,v1,m01,gate)  a=3: inter1(q1,k0,v0,m10,gate)
// proj[a][row][32] fp32 output.
// ---------------------------------------------------------------------------
__global__ __launch_bounds__(256, 2) void attn_kernel(
    const __bf16* __restrict__ wsb,
    const int* __restrict__ m00, const int* __restrict__ m01,
    const int* __restrict__ m10, const int* __restrict__ m11,
    const float* __restrict__ wo00, const float* __restrict__ bo00,
    const float* __restrict__ wo01, const float* __restrict__ bo01,
    const float* __restrict__ wo10, const float* __restrict__ bo10,
    const float* __restrict__ wo11, const float* __restrict__ bo11,
    float* __restrict__ proj)
{
  union Sh {
    struct { int mask[64][68]; __bf16 P[4][64][72]; } a;   // 17408 + 36864 B
    struct { __bf16 O[64][136]; } e;                        // 17408 B
  };
  __shared__ Sh sh;

  const int bx = blockIdx.x;
  const int a  = bx >> 8;
  const int idx = bx & 255;
  const int b = idx >> 3, qt = idx & 7;

  const int t    = threadIdx.x;
  const int lane = t & 63, h = t >> 6;     // h = head = wave
  const int quad = lane >> 4, ln = lane & 15;

  const int qg = (a == 1 || a == 3) ? 1 : 0;
  const int kg = (a == 1 || a == 2) ? 1 : 0;
  const int* msel = (a == 0) ? m00 : (a == 1) ? m11 : (a == 2) ? m01 : m10;
  const float* wo = (a == 0) ? wo00 : (a == 1) ? wo11 : (a == 2) ? wo01 : wo10;
  const float* bo = (a == 0) ? bo00 : (a == 1) ? bo11 : (a == 2) ? bo01 : bo10;
  const bool gate = (a >= 2);

  const __bf16* qb  = wsb + (size_t)(qg * 3 + 0) * (ROWS * D_) + (size_t)(b * N_ + qt * 64) * D_;
  const __bf16* kb  = wsb + (size_t)(kg * 3 + 1) * (ROWS * D_) + (size_t)b * N_ * D_;
  const __bf16* vtb = wsb + (size_t)(kg * 3 + 2) * (ROWS * D_) + (size_t)b * D_ * N_;
  const int* maskb  = msel + (size_t)b * N_ * N_ + (size_t)(qt * 64) * N_;

  // Q fragments: A[m=ln][k=quad*8+j], rows qt*64 + mt*16 + ln, dims h*32..
  bf16x8 qf[4];
  #pragma unroll
  for (int mt = 0; mt < 4; ++mt)
    qf[mt] = *(const bf16x8*)(qb + (size_t)(mt * 16 + ln) * D_ + h * 32 + quad * 8);

  float mrow[4][4], lrow[4][4];
  f32x4 Oacc[4][2];
  #pragma unroll
  for (int mt = 0; mt < 4; ++mt) {
    #pragma unroll
    for (int r = 0; r < 4; ++r) { mrow[mt][r] = -BIGF; lrow[mt][r] = 0.f; }
    f32x4 z = {0.f, 0.f, 0.f, 0.f};
    Oacc[mt][0] = z; Oacc[mt][1] = z;
  }
  const f32x4 zero4 = {0.f, 0.f, 0.f, 0.f};

  for (int ch = 0; ch < 8; ++ch) {
    const int kc = ch * 64;

    // cooperative mask chunk load: 64 rows x 64 ints, coalesced int4
    {
      const int r = t >> 2, cq = (t & 3) * 16;
      const int4* mp = (const int4*)(maskb + (size_t)r * N_ + kc + cq);
      int4* dstp = (int4*)&sh.a.mask[r][cq];
      #pragma unroll
      for (int i = 0; i < 4; ++i) dstp[i] = mp[i];
    }
    __syncthreads();

    // K fragments: B[k=dim][n=key]: lane reads K[key=ln][dim quad*8..+7]
    bf16x8 kf[4];
    #pragma unroll
    for (int nt = 0; nt < 4; ++nt)
      kf[nt] = *(const bf16x8*)(kb + (size_t)(kc + nt * 16 + ln) * D_ + h * 32 + quad * 8);

    #pragma unroll
    for (int mt = 0; mt < 4; ++mt) {
      f32x4 s[4];
      #pragma unroll
      for (int nt = 0; nt < 4; ++nt) s[nt] = mfma16(qf[mt], kf[nt], zero4);

      #pragma unroll
      for (int r = 0; r < 4; ++r) {
        const int row = mt * 16 + quad * 4 + r;
        float lg[4];
        float mx = -3.0e38f;
        #pragma unroll
        for (int nt = 0; nt < 4; ++nt) {
          const int mb = sh.a.mask[row][nt * 16 + ln];
          const float v = s[nt][r] * SCALE_;
          lg[nt] = mb ? v : -BIGF;
          mx = fmaxf(mx, lg[nt]);
        }
        mx = fmaxf(mx, __shfl_xor(mx, 1));
        mx = fmaxf(mx, __shfl_xor(mx, 2));
        mx = fmaxf(mx, __shfl_xor(mx, 4));
        mx = fmaxf(mx, __shfl_xor(mx, 8));
        const float mold = mrow[mt][r];
        const float mnew = fmaxf(mold, mx);
        const float alpha = __expf(mold - mnew);
        mrow[mt][r] = mnew;
        float ssum = 0.f;
        #pragma unroll
        for (int nt = 0; nt < 4; ++nt) {
          const float p = __expf(lg[nt] - mnew);
          ssum += p;
          sh.a.P[h][row][nt * 16 + ln] = (__bf16)p;
        }
        ssum += __shfl_xor(ssum, 1);
        ssum += __shfl_xor(ssum, 2);
        ssum += __shfl_xor(ssum, 4);
        ssum += __shfl_xor(ssum, 8);
        lrow[mt][r] = lrow[mt][r] * alpha + ssum;
        Oacc[mt][0][r] *= alpha;
        Oacc[mt][1][r] *= alpha;
      }
    }
    __syncthreads();   // P visible (cross-lane), mask reads done before next load

    // PV: A = P (from LDS), B = V (vt[dim][key], contiguous 16B)
    #pragma unroll
    for (int ks = 0; ks < 2; ++ks) {
      bf16x8 vf[2];
      #pragma unroll
      for (int vt2 = 0; vt2 < 2; ++vt2)
        vf[vt2] = *(const bf16x8*)(vtb + (size_t)(h * 32 + vt2 * 16 + ln) * N_ + kc + ks * 32 + quad * 8);
      #pragma unroll
      for (int mt = 0; mt < 4; ++mt) {
        bf16x8 pa = *(const bf16x8*)&sh.a.P[h][mt * 16 + ln][ks * 32 + quad * 8];
        #pragma unroll
        for (int vt2 = 0; vt2 < 2; ++vt2)
          Oacc[mt][vt2] = mfma16(pa, vf[vt2], Oacc[mt][vt2]);
      }
    }
  }

  // finalize: O /= l, gating (all-masked row -> 0 when gated)
  float fac[4][4];
  #pragma unroll
  for (int mt = 0; mt < 4; ++mt)
    #pragma unroll
    for (int r = 0; r < 4; ++r) {
      float f = 1.f / lrow[mt][r];
      if (gate && mrow[mt][r] < -1.0e15f) f = 0.f;
      fac[mt][r] = f;
    }

  __syncthreads();   // all waves done with sh.a before overwriting with sh.e
  #pragma unroll
  for (int mt = 0; mt < 4; ++mt)
    #pragma unroll
    for (int vt2 = 0; vt2 < 2; ++vt2)
      #pragma unroll
      for (int r = 0; r < 4; ++r)
        sh.e.O[mt * 16 + quad * 4 + r][h * 32 + vt2 * 16 + ln] =
            (__bf16)(Oacc[mt][vt2][r] * fac[mt][r]);
  __syncthreads();

  // wo projection: wave handles rows h*16..+15, cols 0..31; K=128
  f32x4 pacc[2];
  pacc[0] = zero4; pacc[1] = zero4;
  #pragma unroll
  for (int ks = 0; ks < 4; ++ks) {
    bf16x8 afr = *(const bf16x8*)&sh.e.O[h * 16 + ln][ks * 32 + quad * 8];
    #pragma unroll
    for (int ct = 0; ct < 2; ++ct) {
      bf16x8 bw;
      #pragma unroll
      for (int j = 0; j < 8; ++j)
        bw[j] = (__bf16)wo[(size_t)(ks * 32 + quad * 8 + j) * 32 + ct * 16 + ln];
      pacc[ct] = mfma16(afr, bw, pacc[ct]);
    }
  }
  const int R0g = b * N_ + qt * 64;
  #pragma unroll
  for (int ct = 0; ct < 2; ++ct) {
    const int col = ct * 16 + ln;
    const float bv = bo[col];
    #pragma unroll
    for (int r = 0; r < 4; ++r) {
      const float v = fmaxf(pacc[ct][r] + bv, 0.f);
      proj[(size_t)(a * ROWS + R0g + h * 16 + quad * 4 + r) * 32 + col] = v;
    }
  }
}

// ---------------------------------------------------------------------------
// Kernel 3: out_g = concat(inner_g, inter_g) @ wf_g + bf_g  (no relu)
// block = 2 rows x 128 cols; inner_g = proj[g], inter_g = proj[2+g].
// ---------------------------------------------------------------------------
__global__ __launch_bounds__(256) void outproj_kernel(
    const float* __restrict__ proj,
    const float* __restrict__ wf0, const float* __restrict__ bf0,
    const float* __restrict__ wf1, const float* __restrict__ bf1,
    float* __restrict__ out)
{
  __shared__ float cat[2][2][64];   // [row_in_block][g][c]
  const int t = threadIdx.x;
  const int R = blockIdx.x * 2;
  {
    const int ri = t >> 7, rest = t & 127;
    const int g = rest >> 6, half = (rest >> 5) & 1, c = rest & 31;
    const int a = half ? (2 + g) : g;
    cat[ri][g][half * 32 + c] = proj[(size_t)(a * ROWS + R + ri) * 32 + c];
  }
  __syncthreads();
  const int ri = t >> 7, j = t & 127;
  #pragma unroll
  for (int g = 0; g < 2; ++g) {
    const float* wf  = g ? wf1 : wf0;
    const float* bfp = g ? bf1 : bf0;
    float acc = bfp[j];
    #pragma unroll
    for (int c = 0; c < 64; ++c) acc += cat[ri][g][c] * wf[(size_t)c * 128 + j];
    out[(size_t)g * (ROWS * D_) + (size_t)(R + ri) * D_ + j] = acc;
  }
}

// ---------------------------------------------------------------------------
extern "C" void kernel_launch(void* const* d_in, const int* in_sizes, int n_in,
                              void* d_out, int out_size, void* d_ws, size_t ws_size,
                              hipStream_t stream)
{
  const float* x0 = (const float*)d_in[0];
  const float* x1 = (const float*)d_in[1];
  const int* m00 = (const int*)d_in[2];
  const int* m01 = (const int*)d_in[3];
  const int* m10 = (const int*)d_in[4];
  const int* m11 = (const int*)d_in[5];
  const float* wq0 = (const float*)d_in[6];  const float* bq0 = (const float*)d_in[7];
  const float* wk0 = (const float*)d_in[8];  const float* bk0 = (const float*)d_in[9];
  const float* wv0 = (const float*)d_in[10]; const float* bv0 = (const float*)d_in[11];
  const float* wq1 = (const float*)d_in[12]; const float* bq1 = (const float*)d_in[13];
  const float* wk1 = (const float*)d_in[14]; const float* bk1 = (const float*)d_in[15];
  const float* wv1 = (const float*)d_in[16]; const float* bv1 = (const float*)d_in[17];
  const float* wo00 = (const float*)d_in[18]; const float* bo00 = (const float*)d_in[19];
  const float* wo01 = (const float*)d_in[20]; const float* bo01 = (const float*)d_in[21];
  const float* wo10 = (const float*)d_in[22]; const float* bo10 = (const float*)d_in[23];
  const float* wo11 = (const float*)d_in[24]; const float* bo11 = (const float*)d_in[25];
  const float* wf0 = (const float*)d_in[26]; const float* bf0 = (const float*)d_in[27];
  const float* wf1 = (const float*)d_in[28]; const float* bf1 = (const float*)d_in[29];

  // workspace: 6 bf16 tensors (q0,k0,vt0,q1,k1,vt1) of ROWS*128, then proj fp32
  __bf16* wsb = (__bf16*)d_ws;
  float* proj = (float*)((char*)d_ws + (size_t)6 * ROWS * D_ * 2);   // 24 MB offset

  qkv_kernel<<<dim3(1536), dim3(256), 0, stream>>>(
      x0, x1, wq0, bq0, wk0, bk0, wv0, bv0, wq1, bq1, wk1, bk1, wv1, bv1, wsb);
  attn_kernel<<<dim3(1024), dim3(256), 0, stream>>>(
      wsb, m00, m01, m10, m11,
      wo00, bo00, wo01, bo01, wo10, bo10, wo11, bo11, proj);
  outproj_kernel<<<dim3(8192), dim3(256), 0, stream>>>(
      proj, wf0, bf0, wf1, bf1, (float*)d_out);
}